// Round 5
// baseline (241.646 us; speedup 1.0000x reference)
//
#include <hip/hip_runtime.h>

typedef unsigned long long u64;
typedef unsigned int u32;

#define HH 2048
#define WW 4096
#define MW 66            // u64 words per padded row: 1 guard + 64 data + 1 guard
#define MROWS (HH + 20)  // 10 zero guard rows above and below
#define MASK_WORDS ((size_t)MROWS * MW)
#define THR 10.0f
#define NWORDS (HH * (WW / 64))   // 131072 data words
#define MAIN_BLOCKS 2048          // 8192 waves x 16 word-tasks
#define TASKS_PER_WAVE 16
#define PACK_BLOCKS 1024          // 4096 waves x 8 tiles of 256 px

// ---------------- pack: float image -> 1 bit/pixel mask (ballot) -------------
__global__ __launch_bounds__(256) void pack_masks(const float* __restrict__ gt,
                                                  const float* __restrict__ pred,
                                                  u64* __restrict__ gmask,
                                                  u64* __restrict__ pmask) {
    int l = threadIdx.x & 63;
    int gw = (blockIdx.x * 256 + threadIdx.x) >> 6;  // 0..4095
    #pragma unroll 1
    for (int t = 0; t < 8; ++t) {
        int tile = gw * 8 + t;        // 0..32767, 4 words = 256 px each
        int base = tile * 256;
        u64 g0 = __ballot(gt[base +   0 + l] > 0.5f);
        u64 p0 = __ballot(pred[base +   0 + l] > 0.5f);
        u64 g1 = __ballot(gt[base +  64 + l] > 0.5f);
        u64 p1 = __ballot(pred[base +  64 + l] > 0.5f);
        u64 g2 = __ballot(gt[base + 128 + l] > 0.5f);
        u64 p2 = __ballot(pred[base + 128 + l] > 0.5f);
        u64 g3 = __ballot(gt[base + 192 + l] > 0.5f);
        u64 p3 = __ballot(pred[base + 192 + l] > 0.5f);
        if (l < 4) {
            u64 gv = (l == 0) ? g0 : (l == 1) ? g1 : (l == 2) ? g2 : g3;
            u64 pv = (l == 0) ? p0 : (l == 1) ? p1 : (l == 2) ? p2 : p3;
            int W = tile * 4 + l;                 // data word index
            int y = W >> 6;
            int w = W & 63;
            size_t o = (size_t)(y + 10) * MW + 1 + w;
            gmask[o] = gv;
            pmask[o] = pv;
        }
    }
}

// Branchless 21x21 window min of dy^2+dx^2 from wave-uniform scalar rows.
// q points at padded word w of the CENTER row (pixels of this wave live in
// word q+1). Lane l's window = bits [54+l .. 74+l] of concat(q[0],q[1],q[2]).
// Empty rows yield fake d2 = ady^2 + 121 >= 121, indistinguishable from INF
// after the d2>=100 clamp — safe.
__device__ __forceinline__ u32 scan21(const u64* __restrict__ q, int l, int shl_h) {
    u32 mind2 = 1u << 20;
    #pragma unroll
    for (int ady = 0; ady <= 10; ++ady) {
        const u64* r0 = q - (size_t)ady * MW;
        const u64* r1 = q + (size_t)ady * MW;
        u64 m0 = r0[0] | r1[0];
        u64 m1 = r0[1] | r1[1];
        u64 m2 = r0[2] | r1[2];
        u64 W0  = (m0 >> 54) | (m1 << 10);          // concat bits 54..117 (SALU)
        u64 W1s = ((m1 >> 54) | (m2 << 10)) << 1;   // (bits 118..) << 1   (SALU)
        u32 win = ((u32)(W0 >> l) | (u32)(W1s << shl_h)) & 0x1FFFFFu;
        u32 hi = win >> 10;          // bit j <-> dx = +j
        u32 lo = win & 0x3FFu;       // bit j <-> dx = j-10
        u32 dr = (u32)__ffs(hi) - 1u;        // hi==0 -> huge
        u32 dl = (u32)__clz((int)lo) - 21u;  // lo==0 -> 11
        u32 mdx = dr < dl ? dr : dl;         // <= 11
        u32 d2 = (u32)(ady * ady) + mdx * mdx;
        mind2 = d2 < mind2 ? d2 : mind2;
    }
    return mind2;
}

__device__ __forceinline__ float waveReduceF(float v) {
    #pragma unroll
    for (int o = 32; o > 0; o >>= 1) v += __shfl_down(v, o);
    return v;
}

__global__ __launch_bounds__(256) void dbe_main(const u64* __restrict__ gmask,
                                                const u64* __restrict__ pmask,
                                                float* __restrict__ pn,
                                                float* __restrict__ pd,
                                                float* __restrict__ pf) {
    int l = threadIdx.x & 63;
    int shl_h = 63 - l;
    int gw = (blockIdx.x * 256 + threadIdx.x) >> 6;          // 0..8191
    int task0 = __builtin_amdgcn_readfirstlane(gw) * TASKS_PER_WAVE;

    float num = 0.0f, den = 0.0f, filt = 0.0f;

    #pragma unroll 1
    for (int k = 0; k < TASKS_PER_WAVE; ++k) {
        int t = task0 + k;              // word-task: 16 consecutive words
        int y = t >> 6;
        int w = t & 63;
        const u64* grow = gmask + (size_t)(y + 10) * MW + w;  // uniform ptrs
        const u64* prow = pmask + (size_t)(y + 10) * MW + w;
        u64 gcen = grow[1];             // wave's own 64 pixels
        u64 pcen = prow[1];
        u32 p = (u32)(pcen >> l) & 1u;
        u32 g = (u32)(gcen >> l) & 1u;
        den += (float)(p + g);

        if (pcen) {                     // uniform branch: any pred-fg lane?
            u32 dg = scan21(grow, l, shl_h);           // dist^2 to gt fg
            float Dg = fminf(sqrtf((float)dg), THR);
            num += p ? Dg : 0.0f;                      // ch1
            filt += (p && dg < 100u) ? 1.0f : 0.0f;    // pred & (D_gt < thr)
        }
        if (gcen) {                     // any gt-fg lane?
            u32 dp = scan21(prow, l, shl_h);           // dist^2 to pred fg
            float Dp = fminf(sqrtf((float)dp), THR);
            num += g ? Dp : 0.0f;                      // ch2
        }
    }

    num = waveReduceF(num);
    den = waveReduceF(den);
    filt = waveReduceF(filt);

    __shared__ float sN[4], sD[4], sF[4];
    int lane = threadIdx.x & 63;
    int wid = threadIdx.x >> 6;
    if (lane == 0) { sN[wid] = num; sD[wid] = den; sF[wid] = filt; }
    __syncthreads();
    if (threadIdx.x == 0) {
        pn[blockIdx.x] = sN[0] + sN[1] + sN[2] + sN[3];
        pd[blockIdx.x] = sD[0] + sD[1] + sD[2] + sD[3];
        pf[blockIdx.x] = sF[0] + sF[1] + sF[2] + sF[3];
    }
}

__global__ __launch_bounds__(256) void dbe_reduce(const float* __restrict__ pn,
                                                  const float* __restrict__ pd,
                                                  const float* __restrict__ pf,
                                                  float* __restrict__ out) {
    double n = 0.0, d = 0.0, f = 0.0;
    for (int i = threadIdx.x; i < MAIN_BLOCKS; i += 256) {
        n += (double)pn[i]; d += (double)pd[i]; f += (double)pf[i];
    }
    #pragma unroll
    for (int o = 32; o > 0; o >>= 1) {
        n += __shfl_down(n, o); d += __shfl_down(d, o); f += __shfl_down(f, o);
    }
    __shared__ double sn[4], sd[4], sf[4];
    int lane = threadIdx.x & 63;
    int wid = threadIdx.x >> 6;
    if (lane == 0) { sn[wid] = n; sd[wid] = d; sf[wid] = f; }
    __syncthreads();
    if (threadIdx.x == 0) {
        double N = sn[0] + sn[1] + sn[2] + sn[3];
        double D = sd[0] + sd[1] + sd[2] + sd[3];
        double F = sf[0] + sf[1] + sf[2] + sf[3];
        out[0] = (F == 0.0) ? THR : (float)(N / D);
    }
}

extern "C" void kernel_launch(void* const* d_in, const int* in_sizes, int n_in,
                              void* d_out, int out_size, void* d_ws, size_t ws_size,
                              hipStream_t stream) {
    const float* gt   = (const float*)d_in[0];
    const float* pred = (const float*)d_in[1];
    float* out = (float*)d_out;

    // workspace: pn|pd|pf (3*2048 floats, 24KB) then gmask, pmask
    float* pn = (float*)d_ws;
    float* pd = pn + MAIN_BLOCKS;
    float* pf = pd + MAIN_BLOCKS;
    u64* gmask = (u64*)((char*)d_ws + 3 * MAIN_BLOCKS * sizeof(float));
    u64* pmask = gmask + MASK_WORDS;

    // zero masks (guard rows/words must be 0; pack overwrites all data words)
    hipMemsetAsync(gmask, 0, 2 * MASK_WORDS * sizeof(u64), stream);

    pack_masks<<<PACK_BLOCKS, 256, 0, stream>>>(gt, pred, gmask, pmask);
    dbe_main<<<MAIN_BLOCKS, 256, 0, stream>>>(gmask, pmask, pn, pd, pf);
    dbe_reduce<<<1, 256, 0, stream>>>(pn, pd, pf, out);
}

// Round 6
// 116.910 us; speedup vs baseline: 2.0669x; 2.0669x over previous
//
#include <hip/hip_runtime.h>

typedef unsigned long long u64;
typedef unsigned int u32;

#define HH 2048
#define WW 4096
#define MW 66                      // padded row: 1 guard + 64 data + 1 guard
#define MROWS (HH + 20)            // 10 zero guard rows top/bottom
#define MASK_WORDS ((size_t)MROWS * MW)      // 136488
#define MASK_BYTES (MASK_WORDS * 8)          // 1091904
#define THR 10.0f
#define LIST_CAP (512u * 1024u)    // ~420K expected, huge margin

#define PACK_BLOCKS 2048
#define COMP_BLOCKS 256            // 128 per image, 1024 words/block
#define SCAN_BLOCKS 1024

// ws layout (bytes):
//      0 : u32 cntP, cntG
//    256 : float pn[SCAN_BLOCKS]
//   4352 : float pf[SCAN_BLOCKS]
//  16384 : gmask (MASK_BYTES)
//  16384+MASK_BYTES : pmask
//  then listP (LIST_CAP u32), listG
#define GM_OFF 16384
#define PM_OFF (GM_OFF + MASK_BYTES)
#define LP_OFF (PM_OFF + MASK_BYTES)
#define LG_OFF (LP_OFF + LIST_CAP * 4)

// ---------------- pack: float image -> 1 bit/pixel padded mask ---------------
__global__ __launch_bounds__(256) void pack_masks(const float* __restrict__ gt,
                                                  const float* __restrict__ pred,
                                                  u64* __restrict__ gm,
                                                  u64* __restrict__ pm) {
    int l = threadIdx.x & 63;
    int gw = (blockIdx.x * 256 + threadIdx.x) >> 6;   // 0..8191
    #pragma unroll 1
    for (int t = 0; t < 4; ++t) {
        int tile = gw * 4 + t;                        // 0..32767 (256 px each)
        int base = tile * 256;
        u64 g0 = __ballot(gt[base +   0 + l] > 0.5f);
        u64 g1 = __ballot(gt[base +  64 + l] > 0.5f);
        u64 g2 = __ballot(gt[base + 128 + l] > 0.5f);
        u64 g3 = __ballot(gt[base + 192 + l] > 0.5f);
        u64 p0 = __ballot(pred[base +   0 + l] > 0.5f);
        u64 p1 = __ballot(pred[base +  64 + l] > 0.5f);
        u64 p2 = __ballot(pred[base + 192 - 64 + l] > 0.5f);  // base+128
        u64 p3 = __ballot(pred[base + 192 + l] > 0.5f);
        if (l < 4) {
            u64 gv = (l == 0) ? g0 : (l == 1) ? g1 : (l == 2) ? g2 : g3;
            u64 pv = (l == 0) ? p0 : (l == 1) ? p1 : (l == 2) ? p2 : p3;
            int W = tile * 4 + l;                     // data word 0..131071
            size_t o = (size_t)((W >> 6) + 10) * MW + 1 + (W & 63);
            gm[o] = gv;
            pm[o] = pv;
        }
    }
}

// -------- compact: emit (y<<12|x) for every fg pixel; 1 atomic per block -----
__global__ __launch_bounds__(256) void compact(const u64* __restrict__ gm,
                                               const u64* __restrict__ pm,
                                               u32* __restrict__ cnt,
                                               u32* __restrict__ listP,
                                               u32* __restrict__ listG) {
    bool isPred = blockIdx.x < (COMP_BLOCKS / 2);
    const u64* msk = isPred ? pm : gm;        // membership mask
    u32* lst = isPred ? listP : listG;
    u32* ctr = isPred ? cnt : cnt + 1;
    int wb = (blockIdx.x & (COMP_BLOCKS / 2 - 1)) * 1024;
    int tid = threadIdx.x;

    u64 wv[4];
    u32 pc[4];
    u32 tp = 0;
    #pragma unroll
    for (int j = 0; j < 4; ++j) {
        int W = wb + tid + 256 * j;
        wv[j] = msk[(size_t)((W >> 6) + 10) * MW + 1 + (W & 63)];
        pc[j] = (u32)__popcll(wv[j]);
        tp += pc[j];
    }
    // wave exclusive scan of tp
    u32 s = tp;
    #pragma unroll
    for (int o = 1; o < 64; o <<= 1) {
        u32 v = __shfl_up(s, o);
        if ((tid & 63) >= o) s += v;
    }
    u32 excl = s - tp;
    __shared__ u32 wtot[4], wbase[4], sbase;
    int wid = tid >> 6, lane = tid & 63;
    if (lane == 63) wtot[wid] = s;            // inclusive at lane 63 = total
    __syncthreads();
    if (tid == 0) {
        u32 bt = 0;
        for (int i = 0; i < 4; ++i) { wbase[i] = bt; bt += wtot[i]; }
        sbase = atomicAdd(ctr, bt);
    }
    __syncthreads();
    u32 ptr = sbase + wbase[wid] + excl;
    #pragma unroll
    for (int j = 0; j < 4; ++j) {
        int W = wb + tid + 256 * j;
        u32 yx = ((u32)(W >> 6) << 12) | ((u32)(W & 63) << 6);
        u64 m = wv[j];
        while (m) {
            u32 b = (u32)__ffsll((long long)m) - 1u;
            if (ptr < LIST_CAP) lst[ptr] = yx + b;
            ++ptr;
            m &= m - 1;
        }
    }
}

// ---- per-pixel branchless window scan; |dy|<=9 suffices (d2>=100 clamps) ----
__device__ __forceinline__ u32 scan_d2(const u64* __restrict__ rowc, int x) {
    int b = x + 54;                 // window-start bit (pixel x at bit 64+x)
    int sh = b & 63;
    int shl = 63 - sh;
    const u64* q = rowc + (b >> 6);
    // ady = 0 (2 loads)
    u64 q0 = q[0], q1 = q[1];
    u32 win = (u32)((q0 >> sh) | ((q1 << 1) << shl)) & 0x1FFFFFu;
    u32 hi = win >> 10;                       // dx = 0..10
    u32 lo = win & 0x3FFu;                    // dx = -10..-1
    u32 dr = (u32)__ffs((int)hi) - 1u;        // hi==0 -> huge
    u32 dl = (u32)__clz((int)lo) - 21u;       // lo==0 -> 11
    u32 mdx = dr < dl ? dr : dl;
    u32 mind2 = mdx * mdx;
    #pragma unroll
    for (int ady = 1; ady <= 9; ++ady) {
        const u64* r0 = q - (size_t)ady * MW;
        const u64* r1 = q + (size_t)ady * MW;
        u64 a0 = r0[0] | r1[0];
        u64 a1 = r0[1] | r1[1];
        u32 w = (u32)((a0 >> sh) | ((a1 << 1) << shl)) & 0x1FFFFFu;
        u32 h2 = w >> 10;
        u32 l2 = w & 0x3FFu;
        u32 d1 = (u32)__ffs((int)h2) - 1u;
        u32 d0 = (u32)__clz((int)l2) - 21u;
        u32 m2 = d1 < d0 ? d1 : d0;
        u32 d2 = (u32)(ady * ady) + m2 * m2;
        mind2 = d2 < mind2 ? d2 : mind2;
    }
    return mind2;   // >=100 (incl. empty-window 121) all clamp to D=10
}

__global__ __launch_bounds__(256) void dbe_scan(const u64* __restrict__ gm,
                                                const u64* __restrict__ pm,
                                                const u32* __restrict__ cnt,
                                                const u32* __restrict__ listP,
                                                const u32* __restrict__ listG,
                                                float* __restrict__ pn,
                                                float* __restrict__ pf) {
    u32 cp = cnt[0], cg = cnt[1];
    u32 total = cp + cg;
    float num = 0.0f, filt = 0.0f;

    for (u32 i = blockIdx.x * 256 + threadIdx.x; i < total;
         i += SCAN_BLOCKS * 256) {
        bool isP = i < cp;
        const u32* ep = isP ? (listP + i) : (listG + (i - cp));
        u32 e = *ep;
        u32 x = e & 4095u;
        u32 y = e >> 12;
        const u64* base = isP ? gm : pm;     // pred pixel -> dist to gt fg
        u32 d2 = scan_d2(base + (size_t)(y + 10) * MW, (int)x);
        num += fminf(sqrtf((float)d2), THR);
        filt += (isP && d2 < 100u) ? 1.0f : 0.0f;
    }

    #pragma unroll
    for (int o = 32; o > 0; o >>= 1) {
        num += __shfl_down(num, o);
        filt += __shfl_down(filt, o);
    }
    __shared__ float sN[4], sF[4];
    int lane = threadIdx.x & 63, wid = threadIdx.x >> 6;
    if (lane == 0) { sN[wid] = num; sF[wid] = filt; }
    __syncthreads();
    if (threadIdx.x == 0) {
        pn[blockIdx.x] = sN[0] + sN[1] + sN[2] + sN[3];
        pf[blockIdx.x] = sF[0] + sF[1] + sF[2] + sF[3];
    }
}

__global__ __launch_bounds__(256) void dbe_reduce(const float* __restrict__ pn,
                                                  const float* __restrict__ pf,
                                                  const u32* __restrict__ cnt,
                                                  float* __restrict__ out) {
    double n = 0.0, f = 0.0;
    for (int i = threadIdx.x; i < SCAN_BLOCKS; i += 256) {
        n += (double)pn[i];
        f += (double)pf[i];
    }
    #pragma unroll
    for (int o = 32; o > 0; o >>= 1) {
        n += __shfl_down(n, o);
        f += __shfl_down(f, o);
    }
    __shared__ double sn[4], sf[4];
    int lane = threadIdx.x & 63, wid = threadIdx.x >> 6;
    if (lane == 0) { sn[wid] = n; sf[wid] = f; }
    __syncthreads();
    if (threadIdx.x == 0) {
        double N = sn[0] + sn[1] + sn[2] + sn[3];
        double F = sf[0] + sf[1] + sf[2] + sf[3];
        double den = (double)(cnt[0] + cnt[1]);   // sum(pred)+sum(gt)
        out[0] = (F == 0.0) ? THR : (float)(N / den);
    }
}

extern "C" void kernel_launch(void* const* d_in, const int* in_sizes, int n_in,
                              void* d_out, int out_size, void* d_ws, size_t ws_size,
                              hipStream_t stream) {
    const float* gt   = (const float*)d_in[0];
    const float* pred = (const float*)d_in[1];
    float* out = (float*)d_out;

    char* ws = (char*)d_ws;
    u32* cnt = (u32*)ws;
    float* pn = (float*)(ws + 256);
    float* pf = (float*)(ws + 4352);
    u64* gm = (u64*)(ws + GM_OFF);
    u64* pm = (u64*)(ws + PM_OFF);
    u32* listP = (u32*)(ws + LP_OFF);
    u32* listG = (u32*)(ws + LG_OFF);

    // zero counters + partials + both masks (guards must be 0) in one memset
    hipMemsetAsync(d_ws, 0, LP_OFF, stream);

    pack_masks<<<PACK_BLOCKS, 256, 0, stream>>>(gt, pred, gm, pm);
    compact<<<COMP_BLOCKS, 256, 0, stream>>>(gm, pm, cnt, listP, listG);
    dbe_scan<<<SCAN_BLOCKS, 256, 0, stream>>>(gm, pm, cnt, listP, listG, pn, pf);
    dbe_reduce<<<1, 256, 0, stream>>>(pn, pf, cnt, out);
}